// Round 15
// baseline (92.419 us; speedup 1.0000x reference)
//
#include <hip/hip_runtime.h>

// (B,H,W,C) = (16,512,512,3) float32. 4 warp ops.
// out concat order: 0:(frame1,f01) 1:(frame0,f10) 2:(frame0,ft0) 3:(frame1,ft1)
#define HH 512
#define WW 512
#define NPIX (16 * HH * WW)
#define IMG_DW (HH * WW * 3)     // dwords per image
#define ROWD_G (WW * 3)          // global image row stride in dwords

#define TSX   32                 // output tile width
#define TSY   32                 // output tile height (32x32: apron ratio 3.06x)
#define APRX  12                 // x apron
#define APRY  12                 // y apron
#define LWX   (TSX + 2 * APRX)   // 56: staged region width (px)
#define LWY   (TSY + 2 * APRY)   // 56: staged region height (rows)
#define LSTR  (LWX * 3)          // 168: row stride (16B chunk-aligned: 168%4==0)
#define LDSDW (LWY * LSTR)       // 9408 dwords = 37,632 B -> 4 blocks/CU of 512thr
#define NCHUNK (LDSDW / 4)       // 2352 16B chunks = 4*512 + 304
#define NTHR  512

typedef float fv4 __attribute__((ext_vector_type(4)));
typedef float fv2 __attribute__((ext_vector_type(2)));
typedef fv4 fv4u __attribute__((aligned(4)));
typedef fv2 fv2u __attribute__((aligned(4)));

// Coordinate decomposition for one sample (pure VALU).
#define SCOORD(qy, qx, yl, xl, ay, ax, okv)                                   \
    {                                                                         \
        float fy = floorf(qy); fy = fminf(fmaxf(fy, 0.0f), (float)(HH - 2));  \
        float fx = floorf(qx); fx = fminf(fmaxf(fx, 0.0f), (float)(WW - 2));  \
        ay = fminf(fmaxf((qy) - fy, 0.0f), 1.0f);                             \
        ax = fminf(fmaxf((qx) - fx, 0.0f), 1.0f);                             \
        yl = (int)fy - AY0; xl = (int)fx - AX0;                               \
        okv = (unsigned)yl < (unsigned)(LWY - 1) &&                           \
              (unsigned)xl < (unsigned)(LWX - 1);                             \
    }

// Batched LDS read of one sample's 12 corners into v[12] (6x ds_read2_b32,
// compile-time indices only).
#define LOAD12_LDS(basep, v)                                                  \
    {                                                                         \
        v[0] = (basep)[0];        v[3] = (basep)[3];                          \
        v[1] = (basep)[1];        v[4] = (basep)[4];                          \
        v[2] = (basep)[2];        v[5] = (basep)[5];                          \
        v[6] = (basep)[LSTR];     v[9]  = (basep)[LSTR + 3];                  \
        v[7] = (basep)[LSTR + 1]; v[10] = (basep)[LSTR + 4];                  \
        v[8] = (basep)[LSTR + 2]; v[11] = (basep)[LSTR + 5];                  \
    }

// Global fallback read (rare; exact same math/clipping as reference).
__device__ __forceinline__ void load12_glb(const float* __restrict__ imgb,
                                           int yl, int xl, int AX0, int AY0,
                                           float* __restrict__ v)
{
    const int y0 = yl + AY0, x0 = xl + AX0;
    const float* t  = imgb + ((size_t)y0 * WW + x0) * 3;
    const float* bo = t + WW * 3;
    const fv4u t4 = *(const fv4u*)t;  const fv2u t2 = *(const fv2u*)(t + 4);
    const fv4u b4 = *(const fv4u*)bo; const fv2u b2 = *(const fv2u*)(bo + 4);
    v[0] = t4.x; v[1] = t4.y; v[2] = t4.z; v[3] = t4.w; v[4] = t2.x; v[5] = t2.y;
    v[6] = b4.x; v[7] = b4.y; v[8] = b4.z; v[9] = b4.w; v[10] = b2.x; v[11] = b2.y;
}

#define LERP3(v, ay, ax, r)                                                   \
    {                                                                         \
        _Pragma("unroll")                                                     \
        for (int c = 0; c < 3; ++c) {                                         \
            const float top = v[c]     + (ax) * (v[c + 3] - v[c]);            \
            const float bot = v[c + 6] + (ax) * (v[c + 9] - v[c + 6]);        \
            r[c] = top + (ay) * (bot - top);                                  \
        }                                                                     \
    }

__global__ __launch_bounds__(NTHR, 8) void warp_ilp_kernel(
    const float* __restrict__ frame0, const float* __restrict__ frame1,
    const float* __restrict__ f01, const float* __restrict__ f10,
    const float* __restrict__ ft0, const float* __restrict__ ft1,
    float* __restrict__ out)
{
    __shared__ float lds[LDSDW];   // 37,632 B -> 4 blocks/CU (32 waves, 100%)

    // 8192 blocks; bijective XCD chunking: XCD k gets 1024 contiguous units
    // = 4 whole (fg,b) images (3 MB fits 4 MB per-XCD L2).
    const unsigned bid = blockIdx.x;
    const unsigned v   = (bid & 7u) * 1024u + (bid >> 3);

    const unsigned tile  = v & 255u;   // 16 x 16 tiles per image
    const unsigned img_b = v >> 8;     // 0..31
    const int b  = (int)(img_b & 15u);
    const int fg = (int)(img_b >> 4);  // 0: frame0 ops{1,2}, 1: frame1 ops{0,3}

    const int tx = (int)(tile & 15u);
    const int ty = (int)(tile >> 4);
    const int X0 = tx * TSX, Y0 = ty * TSY;
    const int AX0 = X0 - APRX, AY0 = Y0 - APRY;

    const float* img   = fg ? frame1 : frame0;
    const float* flowA = fg ? f01 : f10;
    const float* flowB = fg ? ft1 : ft0;
    const size_t opA   = fg ? 0 : 1;
    const size_t opB   = fg ? 3 : 2;

    const float* imgb = img + (size_t)b * IMG_DW;

    const int tid = (int)threadIdx.x;
    const int lx = (tid & 15) * 2;     // 16 threads x 2 px cover 32 px row
    const int ly = tid >> 4;           // 32 rows
    const int x = X0 + lx, y = Y0 + ly;
    const size_t pixIn = ((size_t)b * HH + y) * WW + x;

    // Flow loads FIRST (oldest in vmcnt queue): the coord math below waits
    // only for these, not for the glds batch issued after.
    const fv4 a = __builtin_nontemporal_load((const fv4*)(flowA + pixIn * 2));
    const fv4 c = __builtin_nontemporal_load((const fv4*)(flowB + pixIn * 2));

    // ---- Stage apron region HBM -> LDS via global_load_lds (async, 0 VGPR).
    {
        const unsigned wid = __builtin_amdgcn_readfirstlane((unsigned)tid >> 6);
        int D   = tid * 4;
        int row = D / LSTR;
        int rd  = D - row * LSTR;
#pragma unroll
        for (int it = 0; it < 5; ++it) {
            if (it < 4 || tid < (NCHUNK - 4 * NTHR)) {  // 304 tail chunks
                const int gy = min(max(AY0 + row, 0), HH - 1);
                int idx = gy * ROWD_G + AX0 * 3 + rd;
                idx = min(max(idx, 0), IMG_DW - 4);     // fault-safety only
                const float* src = imgb + idx;
                float* dst = (float*)lds + it * (NTHR * 4) + wid * 256;
                __builtin_amdgcn_global_load_lds(
                    (const __attribute__((address_space(1))) void*)src,
                    (__attribute__((address_space(3))) void*)dst, 16, 0, 0);
            }
            row += 12; rd += 32;                        // +2048 dwords
            if (rd >= LSTR) { rd -= LSTR; ++row; }
        }
    }

    // ---- Coordinate math for ALL 4 samples overlaps the glds drain.
    int yl0, xl0, yl1, xl1, yl2, xl2, yl3, xl3;
    float ay0, ax0, ay1, ax1, ay2, ax2, ay3, ax3;
    bool ok0, ok1, ok2, ok3;
    SCOORD((float)y - a.x, (float)x       - a.y, yl0, xl0, ay0, ax0, ok0);
    SCOORD((float)y - a.z, (float)(x + 1) - a.w, yl1, xl1, ay1, ax1, ok1);
    SCOORD((float)y - c.x, (float)x       - c.y, yl2, xl2, ay2, ax2, ok2);
    SCOORD((float)y - c.z, (float)(x + 1) - c.w, yl3, xl3, ay3, ax3, ok3);

    __syncthreads();   // drains the glds batch

    float* oA = out + (opA * NPIX + pixIn) * 3;
    float* oB = out + (opB * NPIX + pixIn) * 3;

    // Op A: batch BOTH samples' 12 ds_read2 back-to-back (one lgkm region),
    // then math, then store. 24-float live set fits the 64-VGPR/8-wave budget.
    {
        float v0[12], v1[12];
        if (__builtin_expect((bool)__all(ok0 & ok1), 1)) {
            const float* t0 = lds + yl0 * LSTR + 3 * xl0;
            const float* t1 = lds + yl1 * LSTR + 3 * xl1;
            LOAD12_LDS(t0, v0);
            LOAD12_LDS(t1, v1);
        } else {
            if (ok0) { const float* t0 = lds + yl0 * LSTR + 3 * xl0; LOAD12_LDS(t0, v0); }
            else       load12_glb(imgb, yl0, xl0, AX0, AY0, v0);
            if (ok1) { const float* t1 = lds + yl1 * LSTR + 3 * xl1; LOAD12_LDS(t1, v1); }
            else       load12_glb(imgb, yl1, xl1, AX0, AY0, v1);
        }
        float res[6];
        LERP3(v0, ay0, ax0, res);
        LERP3(v1, ay1, ax1, (res + 3));
        fv2 s0 = {res[0], res[1]};
        fv2 s1 = {res[2], res[3]};
        fv2 s2 = {res[4], res[5]};
        __builtin_nontemporal_store(s0, (fv2*)oA);
        __builtin_nontemporal_store(s1, (fv2*)oA + 1);
        __builtin_nontemporal_store(s2, (fv2*)oA + 2);
    }
    // Op B: same batching.
    {
        float v0[12], v1[12];
        if (__builtin_expect((bool)__all(ok2 & ok3), 1)) {
            const float* t0 = lds + yl2 * LSTR + 3 * xl2;
            const float* t1 = lds + yl3 * LSTR + 3 * xl3;
            LOAD12_LDS(t0, v0);
            LOAD12_LDS(t1, v1);
        } else {
            if (ok2) { const float* t0 = lds + yl2 * LSTR + 3 * xl2; LOAD12_LDS(t0, v0); }
            else       load12_glb(imgb, yl2, xl2, AX0, AY0, v0);
            if (ok3) { const float* t1 = lds + yl3 * LSTR + 3 * xl3; LOAD12_LDS(t1, v1); }
            else       load12_glb(imgb, yl3, xl3, AX0, AY0, v1);
        }
        float res[6];
        LERP3(v0, ay2, ax2, res);
        LERP3(v1, ay3, ax3, (res + 3));
        fv2 s0 = {res[0], res[1]};
        fv2 s1 = {res[2], res[3]};
        fv2 s2 = {res[4], res[5]};
        __builtin_nontemporal_store(s0, (fv2*)oB);
        __builtin_nontemporal_store(s1, (fv2*)oB + 1);
        __builtin_nontemporal_store(s2, (fv2*)oB + 2);
    }
}

extern "C" void kernel_launch(void* const* d_in, const int* in_sizes, int n_in,
                              void* d_out, int out_size, void* d_ws, size_t ws_size,
                              hipStream_t stream) {
    const float* frame0 = (const float*)d_in[0];
    const float* frame1 = (const float*)d_in[1];
    const float* f01    = (const float*)d_in[2];
    const float* f10    = (const float*)d_in[3];
    const float* ft0    = (const float*)d_in[4];
    const float* ft1    = (const float*)d_in[5];
    float* out = (float*)d_out;

    // 2 frame-groups * 16 b * 256 tiles = 8192 blocks of 512 threads.
    hipLaunchKernelGGL(warp_ilp_kernel, dim3(8192), dim3(NTHR), 0, stream,
                       frame0, frame1, f01, f10, ft0, ft1, out);
}